// Round 7
// baseline (483.457 us; speedup 1.0000x reference)
//
#include <hip/hip_runtime.h>
#include <hip/hip_bf16.h>

// Problem constants (fixed by setup_inputs)
#define T_TOK 2048
#define DDIM  2048
#define IDIM  2816
#define NE    8
#define NPAIR (T_TOK*2)      // 4096 (token, k) pairs
#define GU_N  (2*IDIM)       // 5632

typedef __bf16  bf16x8 __attribute__((ext_vector_type(8)));
typedef float   f32x4  __attribute__((ext_vector_type(4)));
typedef int     int4v  __attribute__((ext_vector_type(4)));
typedef unsigned int uint4v __attribute__((ext_vector_type(4)));

// ws layout (bytes)
#define OFF_A   (64*1024)
#define OFF_GU  (OFF_A  + (size_t)NPAIR*DDIM*2)   // 46.14 MB region (was gu)
#define OFF_H   (OFF_GU + (size_t)NPAIR*GU_N*2)   // h: 23 MB bf16 (pre-swizzled)
#define OFF_YP  (OFF_H  + (size_t)NPAIR*IDIM*2)   // 32 MB region (was yp)
// Fusion frees gu and yp:
//   W13d (46.14 MB) lives at OFF_GU  (written by repack, read by gemm1)
//   W2d  (23.07 MB) lives at OFF_YP  (written by repack, read by gemm2)
// gemm1 writes h directly (act fused); gemm2 atomically adds into out
// (combine fused). All lifetimes disjoint under stream order.
#define W13_DWORDS (NE*(size_t)GU_N*(DDIM/8))   // 11,534,336
#define W2_DWORDS  (NE*(size_t)DDIM*(IDIM/8))   //  5,767,168

__device__ __forceinline__ unsigned short f2bf(float f) {
    __hip_bfloat16 h = __float2bfloat16(f);
    return __builtin_bit_cast(unsigned short, h);
}
__device__ __forceinline__ float bf2f(unsigned short u) {
    unsigned int x = ((unsigned int)u) << 16;
    return __builtin_bit_cast(float, x);
}
__device__ __forceinline__ unsigned int pack2bf(float lo, float hi) {
    return ((unsigned int)f2bf(hi) << 16) | (unsigned int)f2bf(lo);
}
// async global->LDS, 16B per lane; LDS dest must be wave-uniform-base + lane*16
__device__ __forceinline__ void gload_lds16(const void* g, void* l) {
    __builtin_amdgcn_global_load_lds(
        (const __attribute__((address_space(1))) void*)g,
        (__attribute__((address_space(3))) void*)l, 16, 0, 0);
}

// ---------------- routing: stable compaction of 4096 pairs by expert ---------
// meta: [0..7]=cnt, [8..15]=off (exclusive prefix), [64..64+4095]=list (pair idx)
__global__ void route_kernel(const int* __restrict__ ids, int* __restrict__ meta) {
    __shared__ int histL[NE][256];
    __shared__ int totals[NE];
    __shared__ int offsS[NE];
    const int tid = threadIdx.x;
    for (int e = 0; e < NE; ++e) histL[e][tid] = 0;
    for (int j = 0; j < 16; ++j) {
        int id = ids[tid*16 + j];
        histL[id][tid]++;
    }
    __syncthreads();
    if (tid < NE) {
        int run = 0;
        for (int i = 0; i < 256; ++i) { int v = histL[tid][i]; histL[tid][i] = run; run += v; }
        totals[tid] = run;
    }
    __syncthreads();
    if (tid == 0) {
        int run = 0;
        for (int e = 0; e < NE; ++e) {
            offsS[e] = run;
            meta[e] = totals[e];
            meta[8+e] = run;
            run += totals[e];
        }
    }
    __syncthreads();
    for (int j = 0; j < 16; ++j) {
        int p = tid*16 + j;
        int id = ids[p];
        int local = histL[id][tid];
        histL[id][tid] = local + 1;
        meta[64 + offsS[id] + local] = p;
    }
}

// ---------------- gather: x rows -> compact PRE-SWIZZLED bf16 A matrix -------
// logical col-byte cb of row r stored at (cb&~127) | ((cb&127) ^ ((r&7)<<4))
__global__ void gather_kernel(const float* __restrict__ x, const int* __restrict__ meta,
                              unsigned short* __restrict__ Aall) {
    const int r = blockIdx.x;
    const int p = meta[64 + r];
    const int t = p >> 1;
    const int c = threadIdx.x * 8;
    const float4* src = (const float4*)(x + (size_t)t*DDIM + c);
    float4 f0 = src[0], f1 = src[1];
    unsigned short o[8];
    o[0]=f2bf(f0.x); o[1]=f2bf(f0.y); o[2]=f2bf(f0.z); o[3]=f2bf(f0.w);
    o[4]=f2bf(f1.x); o[5]=f2bf(f1.y); o[6]=f2bf(f1.z); o[7]=f2bf(f1.w);
    int cb  = c * 2;
    int cbs = (cb & ~127) | ((cb & 127) ^ ((r & 7) << 4));
    *(uint4v*)((char*)Aall + (size_t)r*(DDIM*2) + cbs) = *(uint4v*)o;
}

// ---------------- repack: 4x int32 (2 nibbles each) -> 1 uint32 (8 nibbles) --
// 4 dense words per thread: 64B coalesced in, 16B dwordx4 out.
__global__ void repack_kernel(const int* __restrict__ src,
                              unsigned int* __restrict__ dst, int nwords4) {
    const int i4 = blockIdx.x * 256 + threadIdx.x;
    if (i4 >= nwords4) return;
    const int4v* s = (const int4v*)(src + (size_t)i4*16);
    uint4v d;
#pragma unroll
    for (int q = 0; q < 4; ++q) {
        int4v p = s[q];
        d[q] = ((unsigned int)p[0] & 0xFFu)
             | (((unsigned int)p[1] & 0xFFu) << 8)
             | (((unsigned int)p[2] & 0xFFu) << 16)
             | (((unsigned int)p[3] & 0xFFu) << 24);
    }
    *(uint4v*)(dst + (size_t)i4*4) = d;
}

// ---------------- zero the output (gemm2 accumulates atomically) -------------
__global__ void zero_kernel(float* __restrict__ out) {
    const int i = blockIdx.x * 256 + threadIdx.x;
    ((f32x4*)out)[i] = (f32x4)0.0f;
}

// ============ pipelined dequant-GEMM macros (shared by gemm1/gemm2) ==========
// LOADB: ONE dwordx4 of dense-packed B (32 weights) + scale/zp for K-tile KT
#define LOADB(PK, SS, ZZ, KT)  do {                                        \
    PK = *(const uint4v*)(bgp + (size_t)(KT)*8);                           \
    int _g = (KT) >> 1;                                                    \
    SS = sp[_g]; ZZ = zp[_g];                                              \
} while (0)

// ISSUE_A: async-copy A K-slab KT into As[SEL] (linear copy of pre-swizzled rows)
#define ISSUE_A(SEL, KT) do {                                              \
    _Pragma("unroll")                                                      \
    for (int _i = 0; _i < 4; ++_i)                                         \
        gload_lds16(a_src[_i] + (size_t)(KT)*128,                          \
                    (char*)&As[SEL][0] + wv*4096 + _i*1024 + lane*16);     \
} while (0)

// DEQ: nibble-plane split -> byte extracts (v_cvt_f32_ubyte candidates)
#define DEQ(PK, SS, ZZ, BWP) do {                                          \
    float _s = SS, _c = -(ZZ)*(SS);                                        \
    _Pragma("unroll")                                                      \
    for (int _q = 0; _q < 4; ++_q) {                                       \
        unsigned int _w  = PK[_q];                                         \
        unsigned int _lo = _w & 0x0F0F0F0Fu;                               \
        unsigned int _hi = (_w >> 4) & 0x0F0F0F0Fu;                        \
        _Pragma("unroll")                                                  \
        for (int _j = 0; _j < 4; ++_j) {                                   \
            float _flo = (float)((_lo >> (8*_j)) & 0xFFu);                 \
            float _fhi = (float)((_hi >> (8*_j)) & 0xFFu);                 \
            BWP[_q*4 + _j] = pack2bf(fmaf(_flo, _s, _c),                   \
                                     fmaf(_fhi, _s, _c));                  \
        }                                                                  \
    }                                                                      \
} while (0)

#define WRITE_BS(BWP) do {                                                 \
    _Pragma("unroll")                                                      \
    for (int _q = 0; _q < 4; ++_q) {                                       \
        int _cb  = ahalf*64 + _q*16;                                       \
        int _cbs = _cb ^ swzB;                                             \
        *(uint4v*)(&Bs[arow*64 + (_cbs >> 1)]) = *(uint4v*)(&BWP[_q*4]);   \
    }                                                                      \
} while (0)

// MFMA_STEP: ds_read frags (A xor uses global-row parity base7+row) and accumulate
#define MFMA_STEP(SEL) do {                                                \
    _Pragma("unroll")                                                      \
    for (int _kk = 0; _kk < 2; ++_kk) {                                    \
        bf16x8 _af[4], _bf[4];                                             \
        const int _kbyte = _kk*64 + lk*16;                                 \
        _Pragma("unroll")                                                  \
        for (int _mi = 0; _mi < 4; ++_mi) {                                \
            int _row = wm + _mi*16 + lr;                                   \
            int _b = _kbyte ^ (((_row + base7) & 7) << 4);                 \
            _af[_mi] = *(const bf16x8*)(&As[SEL][_row*64 + (_b >> 1)]);    \
        }                                                                  \
        _Pragma("unroll")                                                  \
        for (int _nj = 0; _nj < 4; ++_nj) {                                \
            int _row = wn + _nj*16 + lr;                                   \
            int _b = _kbyte ^ ((_row & 7) << 4);                           \
            _bf[_nj] = *(const bf16x8*)(&Bs[_row*64 + (_b >> 1)]);         \
        }                                                                  \
        _Pragma("unroll")                                                  \
        for (int _mi = 0; _mi < 4; ++_mi)                                  \
            _Pragma("unroll")                                              \
            for (int _nj = 0; _nj < 4; ++_nj)                              \
                acc[_mi][_nj] = __builtin_amdgcn_mfma_f32_16x16x32_bf16(   \
                    _af[_mi], _bf[_nj], acc[_mi][_nj], 0, 0, 0);           \
    }                                                                      \
} while (0)

// One K-step (R0 proven order — best 2-barrier schedule tested R0..R4)
#define STEP(T, SELC, SELN, PKC, sC, zC, PKN, sN, zN) do {                 \
    if ((T) > 0) __syncthreads();                                          \
    int _ktn = (T)+1 < NT ? (T)+1 : NT-1;                                  \
    ISSUE_A(SELN, _ktn);                                                   \
    LOADB(PKN, sN, zN, _ktn);                                              \
    unsigned int _bw[16];                                                  \
    DEQ(PKC, sC, zC, _bw);                                                 \
    WRITE_BS(_bw);                                                         \
    __syncthreads();                                                       \
    MFMA_STEP(SELC);                                                       \
} while (0)

// ---------------- GEMM1 (act fused): writes h = silu(g)*u directly ----------
// Block covers B-rows {nx*64+c} (gate) and {IDIM+nx*64+c} (up), c in [0,64).
// Bs rows 0-63 = gate (consumed by wn=0 waves), 64-127 = up (wn=64 waves) —
// both wave groups compute the SAME 64 h-columns; epilogue exchanges via LDS.
__launch_bounds__(256, 3)
__global__ void gemm1_kernel(const unsigned short* __restrict__ Aall,
                             const unsigned int* __restrict__ wd,
                             const float* __restrict__ wsc,
                             const float* __restrict__ wzp,
                             const int* __restrict__ meta,
                             unsigned short* __restrict__ h) {
    // XCD-aware remap (R4-proven: FETCH 393->207 on this grid shape).
    // Panels (e,nx) get a contiguous 32-m-block run on ONE XCD.
    const unsigned int l = blockIdx.x + 44u*(blockIdx.y + 32u*blockIdx.z);
    const int xcd   = l & 7;
    const int j     = l >> 3;              // [0, 1408)
    const int panel = xcd + 8*(j >> 5);    // [0, 352)
    const int e   = panel / 44;
    const int nx  = panel % 44;            // h-column block: cols [nx*64, nx*64+64)
    const int m0  = (j & 31) * 128;
    const int cnt = meta[e];
    if (m0 >= cnt) return;
    const int off = meta[8 + e];
    const int tid = threadIdx.x;

    __shared__ unsigned short As[2][128*64];   // 32 KB (reused as f32 uf in epilogue)
    __shared__ unsigned short Bs[128*64];      // 16 KB (reused as bf16 hb in epilogue)

    f32x4 acc[4][4];
#pragma unroll
    for (int i = 0; i < 4; ++i)
#pragma unroll
        for (int jj = 0; jj < 4; ++jj) acc[i][jj] = (f32x4)0.0f;

    // B staging: arow<64 -> gate row nx*64+arow; arow>=64 -> up row IDIM+nx*64+arow-64
    const int arow  = tid >> 1;
    const int ahalf = tid & 1;
    const int brow_g = (arow < 64) ? (nx*64 + arow) : (IDIM + nx*64 + (arow - 64));
    const unsigned int* bgp = wd + ((size_t)e*GU_N + brow_g)*(DDIM/8) + ahalf*4;
    const float* sp = wsc + ((size_t)e*GU_N + brow_g)*(DDIM/128);
    const float* zp = wzp + ((size_t)e*GU_N + brow_g)*(DDIM/128);
    const int swzB  = (arow & 7) << 4;

    // A async-copy mapping
    const int lane = tid & 63;
    const int wv   = tid >> 6;
    const char* a_src[4];
#pragma unroll
    for (int i = 0; i < 4; ++i) {
        int lrow  = wv*32 + i*8 + (lane >> 3);
        int garow = off + m0 + lrow; if (garow > NPAIR-1) garow = NPAIR-1;
        a_src[i] = (const char*)Aall + (size_t)garow*(DDIM*2) + (lane & 7)*16;
    }
    const int base7 = (off + m0) & 7;

    const int wm = (wv >> 1) * 64, wn = (wv & 1) * 64;
    const int lr = lane & 15, lk = lane >> 4;

    const int NT = DDIM/64;   // 32 (even)
    uint4v pkX, pkY;
    float sX, zX, sY, zY;

    ISSUE_A(0, 0);
    LOADB(pkX, sX, zX, 0);
    for (int kt = 0; kt < NT; kt += 2) {
        STEP(kt,   0, 1, pkX, sX, zX, pkY, sY, zY);
        STEP(kt+1, 1, 0, pkY, sY, zY, pkX, sX, zX);
    }
    __syncthreads();   // drain trailing DMA prefetch before LDS reuse

    // ---- fused activation epilogue ----
    // Phase 1: up-waves (wn==64) publish acc to LDS as f32 [128][64]
    float* uf = (float*)&As[0][0];
    if (wn == 64) {
#pragma unroll
        for (int mi = 0; mi < 4; ++mi)
#pragma unroll
            for (int nj = 0; nj < 4; ++nj) {
                f32x4 v = acc[mi][nj];
                int c = nj*16 + lr;
#pragma unroll
                for (int r = 0; r < 4; ++r)
                    uf[(wm + mi*16 + lk*4 + r)*64 + c] = v[r];
            }
    }
    __syncthreads();
    // Phase 2: gate-waves compute h = silu(g)*u -> LDS bf16 [128][64]
    unsigned short* hb = (unsigned short*)Bs;
    if (wn == 0) {
#pragma unroll
        for (int mi = 0; mi < 4; ++mi)
#pragma unroll
            for (int nj = 0; nj < 4; ++nj) {
                f32x4 v = acc[mi][nj];
                int c = nj*16 + lr;
#pragma unroll
                for (int r = 0; r < 4; ++r) {
                    int row = wm + mi*16 + lk*4 + r;
                    float g = v[r];
                    float u = uf[row*64 + c];
                    float sg = g / (1.0f + __expf(-g));
                    hb[row*64 + c] = f2bf(sg * u);
                }
            }
    }
    __syncthreads();
    // Phase 3: coalesced copy LDS -> h with gemm2's pre-swizzle
    // (block's 128B col window is exactly the 128B swizzle period)
#pragma unroll
    for (int q = 0; q < 4; ++q) {
        int ci  = tid + 256*q;        // 1024 chunks of 16B
        int row = ci >> 3;
        int k16 = ci & 7;
        if (m0 + row < cnt) {
            int grow = off + m0 + row;
            int cbs  = (k16*16) ^ ((grow & 7) << 4);
            *(uint4v*)((char*)h + (size_t)grow*(IDIM*2) + nx*128 + cbs) =
                *(uint4v*)&hb[row*64 + k16*8];
        }
    }
}

// ---------------- GEMM2 (combine fused): atomic-adds tw-weighted rows --------
__launch_bounds__(256, 3)
__global__ void gemm2_kernel(const unsigned short* __restrict__ h,
                             const unsigned int* __restrict__ wd,
                             const float* __restrict__ wsc,
                             const float* __restrict__ wzp,
                             const float* __restrict__ tw,
                             const int* __restrict__ meta,
                             float* __restrict__ out) {
    // XCD-aware remap (grid 16 x 32 x 8)
    const unsigned int l = blockIdx.x + 16u*(blockIdx.y + 32u*blockIdx.z);
    const int xcd   = l & 7;
    const int j     = l >> 3;              // [0, 512)
    const int panel = xcd + 8*(j >> 5);    // [0, 128)
    const int e   = panel / 16;
    const int n0  = (panel % 16) * 128;
    const int m0  = (j & 31) * 128;
    const int cnt = meta[e];
    if (m0 >= cnt) return;
    const int off = meta[8 + e];
    const int tid = threadIdx.x;

    __shared__ unsigned short As[2][128*64];
    __shared__ unsigned short Bs[128*64];

    f32x4 acc[4][4];
#pragma unroll
    for (int i = 0; i < 4; ++i)
#pragma unroll
        for (int jj = 0; jj < 4; ++jj) acc[i][jj] = (f32x4)0.0f;

    const int arow  = tid >> 1;
    const int ahalf = tid & 1;
    const int gbrow = n0 + arow;
    const unsigned int* bgp = wd + ((size_t)e*DDIM + gbrow)*(IDIM/8) + ahalf*4;
    const float* sp = wsc + ((size_t)e*DDIM + gbrow)*(IDIM/128);
    const float* zp = wzp + ((size_t)e*DDIM + gbrow)*(IDIM/128);
    const int swzB  = (arow & 7) << 4;

    const int lane = tid & 63;
    const int wv   = tid >> 6;
    const char* a_src[4];
#pragma unroll
    for (int i = 0; i < 4; ++i) {
        int lrow  = wv*32 + i*8 + (lane >> 3);
        int garow = off + m0 + lrow; if (garow > NPAIR-1) garow = NPAIR-1;
        a_src[i] = (const char*)h + (size_t)garow*(IDIM*2) + (lane & 7)*16;
    }
    const int base7 = (off + m0) & 7;

    const int wm = (wv >> 1) * 64, wn = (wv & 1) * 64;
    const int lr = lane & 15, lk = lane >> 4;

    const int NT = IDIM/64;   // 44 (even)
    uint4v pkX, pkY;
    float sX, zX, sY, zY;

    ISSUE_A(0, 0);
    LOADB(pkX, sX, zX, 0);
    for (int kt = 0; kt < NT; kt += 2) {
        STEP(kt,   0, 1, pkX, sX, zX, pkY, sY, zY);
        STEP(kt+1, 1, 0, pkY, sY, zY, pkX, sX, zX);
    }
    __syncthreads();   // drain trailing DMA prefetch before endpgm

    // epilogue: out[token] += tw[p] * y  (2 addends + zero base -> exact)
#pragma unroll
    for (int mi = 0; mi < 4; ++mi)
#pragma unroll
        for (int nj = 0; nj < 4; ++nj) {
            f32x4 v = acc[mi][nj];
            int col = n0 + wn + nj*16 + lr;
#pragma unroll
            for (int r = 0; r < 4; ++r) {
                int row = wm + mi*16 + lk*4 + r;
                if (m0 + row < cnt) {
                    int p = meta[64 + off + m0 + row];
                    float w = tw[p];
                    unsafeAtomicAdd(&out[(size_t)(p >> 1)*DDIM + col], v[r] * w);
                }
            }
        }
}

extern "C" void kernel_launch(void* const* d_in, const int* in_sizes, int n_in,
                              void* d_out, int out_size, void* d_ws, size_t ws_size,
                              hipStream_t stream) {
    const float* x    = (const float*)d_in[0];
    const int*   ids  = (const int*)d_in[1];
    const float* tw   = (const float*)d_in[2];
    const int*   w13p = (const int*)d_in[3];
    const float* w13s = (const float*)d_in[4];
    const float* w13z = (const float*)d_in[5];
    const int*   w2p  = (const int*)d_in[6];
    const float* w2s  = (const float*)d_in[7];
    const float* w2z  = (const float*)d_in[8];
    float* out = (float*)d_out;

    char* ws = (char*)d_ws;
    int* meta = (int*)ws;
    unsigned short* Aall = (unsigned short*)(ws + OFF_A);
    unsigned short* h    = (unsigned short*)(ws + OFF_H);
    unsigned int* W13d   = (unsigned int*)(ws + OFF_GU);   // freed by act-fusion
    unsigned int* W2d    = (unsigned int*)(ws + OFF_YP);   // freed by combine-fusion

    route_kernel<<<1, 256, 0, stream>>>(ids, meta);
    gather_kernel<<<NPAIR, 256, 0, stream>>>(x, meta, Aall);
    repack_kernel<<<(int)(W13_DWORDS/1024), 256, 0, stream>>>(w13p, W13d, (int)(W13_DWORDS/4));
    gemm1_kernel<<<dim3(44, NPAIR/128, NE), 256, 0, stream>>>(Aall, W13d, w13s, w13z, meta, h);
    repack_kernel<<<(int)(W2_DWORDS/1024), 256, 0, stream>>>(w2p, W2d, (int)(W2_DWORDS/4));
    zero_kernel<<<(T_TOK*DDIM/4)/256, 256, 0, stream>>>(out);
    gemm2_kernel<<<dim3(DDIM/128, NPAIR/128, NE), 256, 0, stream>>>(h, W2d, w2s, w2z, tw, meta, out);
}